// Round 4
// baseline (279.630 us; speedup 1.0000x reference)
//
#include <hip/hip_runtime.h>
#include <hip/hip_bf16.h>

#define B_DIM 128
#define S_DIM 64
#define DIN   2048
#define DOUT  2048
#define NLAYERS 64

#define BM 128
#define BN 128
#define BK 64
#define NK (DIN / BK)
#define NTILES (S_DIM * (DOUT / BN))   // 1024
#define NXCD 8

typedef __bf16 bf16_t;
typedef __attribute__((ext_vector_type(8))) bf16_t bf16x8;
typedef __attribute__((ext_vector_type(4))) float f32x4;

// Parallel rank sort: perm = positions ordered by (layer, s).
__global__ void rank_sort(const int* __restrict__ layer_idx, int* __restrict__ perm) {
    __shared__ int L[S_DIM];
    const int s = threadIdx.x;
    L[s] = layer_idx[s];
    __syncthreads();
    const int mine = L[s];
    int rank = 0;
    #pragma unroll
    for (int t = 0; t < S_DIM; ++t) {
        const int lt = L[t];
        rank += (lt < mine || (lt == mine && t < s)) ? 1 : 0;
    }
    perm[rank] = s;
}

// Streaming pre-pass: x fp32 -> bf16 (halves L2 working set + GEMM A bytes).
__global__ void convert_x(const float* __restrict__ x, bf16_t* __restrict__ x16) {
    const size_t i = ((size_t)blockIdx.x * 256 + threadIdx.x) * 8;
    f32x4 a = *(const f32x4*)(x + i);
    f32x4 b = *(const f32x4*)(x + i + 4);
    bf16x8 v;
    #pragma unroll
    for (int j = 0; j < 4; ++j) { v[j] = (bf16_t)a[j]; v[j + 4] = (bf16_t)b[j]; }
    *(bf16x8*)(x16 + i) = v;
}

template <typename T>
__device__ __forceinline__ T ntload(const T* p) { return __builtin_nontemporal_load(p); }

// One 128x128 output tile per block. T14 pipeline + T1 XCD-chunked swizzle.
// XBF16: A comes from the pre-converted bf16 x; weights are nt-loaded so the
// streaming 1GB weight traffic does not evict the shared x slices from L2.
template <bool XBF16>
__launch_bounds__(256, 2)
__global__ void flex_linear_gemm(const float* __restrict__ x,
                                 const bf16_t* __restrict__ x16,
                                 const float* __restrict__ w,
                                 const int* __restrict__ layer_idx,
                                 const int* __restrict__ perm,
                                 float* __restrict__ out) {
    __shared__ bf16_t Alds[BM * BK];  // XOR-swizzled row-major [128][64]
    __shared__ bf16_t Blds[BN * BK];

    // ---- XCD-chunked swizzle (1024 % 8 == 0 -> bijective) ----
    const int orig = blockIdx.x;
    const int xcd  = orig & (NXCD - 1);
    const int slot = orig >> 3;
    const int tile = xcd * (NTILES / NXCD) + slot;
    const int yy   = tile >> 4;           // sorted-position rank
    const int nb   = tile & 15;           // output column block

    const int s  = perm[yy];
    const int layer = layer_idx[s];

    const float* Bg = w + (size_t)layer * (size_t)(DOUT * DIN) + (size_t)(nb * BN) * DIN;

    const int tid  = threadIdx.x;
    const int lane = tid & 63;
    const int wave = tid >> 6;
    const int wr = (wave >> 1) * 64;
    const int wc = (wave & 1) * 64;
    const int lrow = lane & 15;
    const int lk   = (lane >> 4) * 8;

    // ---- hoisted addresses ----
    int offW[4];
    const float*  pA[4];
    const bf16_t* pA16[4];
    const float*  pB[4];
    #pragma unroll
    for (int i = 0; i < 4; ++i) {
        const int row = (tid >> 3) + 32 * i;   // 0..127  (b index for A, o for B)
        const int kc8 = (tid & 7) * 8;
        offW[i] = (row * BK + kc8) ^ ((row & 7) << 3);
        const size_t aoff = (size_t)row * (S_DIM * DIN) + (size_t)s * DIN + kc8;
        pA[i]   = x   + aoff;
        pA16[i] = x16 + aoff;
        pB[i]   = Bg + (size_t)row * DIN + kc8;
    }
    int offA[2][4], offB[2][4];
    #pragma unroll
    for (int kk = 0; kk < 2; ++kk) {
        #pragma unroll
        for (int m = 0; m < 4; ++m) {
            const int ra = wr + m * 16 + lrow;
            const int rb = wc + m * 16 + lrow;
            offA[kk][m] = (ra * BK + kk * 32 + lk) ^ ((ra & 7) << 3);
            offB[kk][m] = (rb * BK + kk * 32 + lk) ^ ((rb & 7) << 3);
        }
    }

    bf16x8 RA16[4];           // in-flight A (bf16 path)
    f32x4  RA[8];             // in-flight A (fp32 fallback)
    f32x4  RB[8];             // in-flight B (always fp32, nt)
    f32x4  acc[4][4] = {};

    auto issue = [&](int kb) {
        const int koff = kb * BK;
        #pragma unroll
        for (int i = 0; i < 4; ++i) {
            if constexpr (XBF16) {
                RA16[i] = *(const bf16x8*)(pA16[i] + koff);
            } else {
                const float* a = pA[i] + koff;
                RA[2 * i]     = *(const f32x4*)a;
                RA[2 * i + 1] = *(const f32x4*)(a + 4);
            }
            const float* b = pB[i] + koff;
            RB[2 * i]     = ntload((const f32x4*)b);
            RB[2 * i + 1] = ntload((const f32x4*)(b + 4));
        }
    };
    auto cvt_write = [&]() {
        #pragma unroll
        for (int i = 0; i < 4; ++i) {
            bf16x8 vb;
            #pragma unroll
            for (int j = 0; j < 4; ++j) {
                vb[j]     = (bf16_t)RB[2 * i][j];
                vb[j + 4] = (bf16_t)RB[2 * i + 1][j];
            }
            if constexpr (XBF16) {
                *(bf16x8*)&Alds[offW[i]] = RA16[i];
            } else {
                bf16x8 va;
                #pragma unroll
                for (int j = 0; j < 4; ++j) {
                    va[j]     = (bf16_t)RA[2 * i][j];
                    va[j + 4] = (bf16_t)RA[2 * i + 1][j];
                }
                *(bf16x8*)&Alds[offW[i]] = va;
            }
            *(bf16x8*)&Blds[offW[i]] = vb;
        }
    };
    auto compute = [&]() {
        #pragma unroll
        for (int kk = 0; kk < 2; ++kk) {
            bf16x8 af[4], bfr[4];
            #pragma unroll
            for (int m = 0; m < 4; ++m) {
                af[m]  = *(const bf16x8*)&Alds[offA[kk][m]];
                bfr[m] = *(const bf16x8*)&Blds[offB[kk][m]];
            }
            #pragma unroll
            for (int m = 0; m < 4; ++m)
                #pragma unroll
                for (int n = 0; n < 4; ++n)
                    acc[m][n] = __builtin_amdgcn_mfma_f32_16x16x32_bf16(af[m], bfr[n], acc[m][n], 0, 0, 0);
        }
    };

    // ---- pipelined main loop: 2 barriers per K-step ----
    issue(0);
    cvt_write();
    for (int kb = 0; kb < NK - 1; ++kb) {
        __syncthreads();
        issue(kb + 1);
        compute();
        __syncthreads();
        cvt_write();
    }
    __syncthreads();
    compute();

    // ---- epilogue (nt stores: out never re-read; keep L2 for x) ----
    float* Og = out + (size_t)s * DOUT + (size_t)(nb * BN);
    #pragma unroll
    for (int m = 0; m < 4; ++m) {
        const int rb = wr + m * 16 + (lane >> 4) * 4;
        #pragma unroll
        for (int r = 0; r < 4; ++r) {
            float* orow = Og + (size_t)(rb + r) * (S_DIM * DOUT);
            #pragma unroll
            for (int n = 0; n < 4; ++n)
                __builtin_nontemporal_store(acc[m][n][r], &orow[wc + n * 16 + (lane & 15)]);
        }
    }
}

extern "C" void kernel_launch(void* const* d_in, const int* in_sizes, int n_in,
                              void* d_out, int out_size, void* d_ws, size_t ws_size,
                              hipStream_t stream) {
    const float* x         = (const float*)d_in[0];
    const float* w         = (const float*)d_in[1];
    const int*   layer_idx = (const int*)d_in[2];
    float*       out       = (float*)d_out;

    int*    perm = (int*)d_ws;                            // [0, 256) bytes
    bf16_t* x16  = (bf16_t*)((char*)d_ws + 512);          // 32 MB, 512-aligned
    const size_t need = 512 + (size_t)B_DIM * S_DIM * DIN * sizeof(bf16_t);

    rank_sort<<<1, S_DIM, 0, stream>>>(layer_idx, perm);

    if (ws_size >= need) {
        convert_x<<<(B_DIM * S_DIM * DIN / 8) / 256, 256, 0, stream>>>(x, x16);
        flex_linear_gemm<true><<<NTILES, dim3(256), 0, stream>>>(x, x16, w, layer_idx, perm, out);
    } else {
        flex_linear_gemm<false><<<NTILES, dim3(256), 0, stream>>>(x, x16, w, layer_idx, perm, out);
    }
}

// Round 5
// 228.599 us; speedup vs baseline: 1.2232x; 1.2232x over previous
//
#include <hip/hip_runtime.h>
#include <hip/hip_bf16.h>

#define B_DIM 128
#define S_DIM 64
#define DIN   2048
#define DOUT  2048
#define NLAYERS 64

#define BM 128
#define BN 64
#define BK 64
#define NK (DIN / BK)
#define TPP (DOUT / BN)                 // tiles per position = 32
#define NTILES (S_DIM * TPP)            // 2048
#define NXCD 8
// LDS pad so exactly 2 blocks/CU fit (160/56 = 2): controls active-position
// count per XCD at 2 (x+weight hot set ~2MB < 4MB L2).
#define APAD 16384                      // 32 KB of bf16 padding

typedef __bf16 bf16_t;
typedef __attribute__((ext_vector_type(8))) bf16_t bf16x8;
typedef __attribute__((ext_vector_type(4))) float f32x4;

// Parallel rank sort: perm = positions ordered by (layer, s).
__global__ void rank_sort(const int* __restrict__ layer_idx, int* __restrict__ perm) {
    __shared__ int L[S_DIM];
    const int s = threadIdx.x;
    L[s] = layer_idx[s];
    __syncthreads();
    const int mine = L[s];
    int rank = 0;
    #pragma unroll
    for (int t = 0; t < S_DIM; ++t) {
        const int lt = L[t];
        rank += (lt < mine || (lt == mine && t < s)) ? 1 : 0;
    }
    perm[rank] = s;
}

// Streaming pre-pass: x fp32 -> bf16 (halves x bytes and L2 working set).
__global__ void convert_x(const float* __restrict__ x, bf16_t* __restrict__ x16) {
    const size_t i = ((size_t)blockIdx.x * 256 + threadIdx.x) * 8;
    f32x4 a = *(const f32x4*)(x + i);
    f32x4 b = *(const f32x4*)(x + i + 4);
    bf16x8 v;
    #pragma unroll
    for (int j = 0; j < 4; ++j) { v[j] = (bf16_t)a[j]; v[j + 4] = (bf16_t)b[j]; }
    *(bf16x8*)(x16 + i) = v;
}

// 128x64 output tile per block (BN=64 -> 32 tiles/position -> only 2 active
// positions per XCD -> L2-fitting working set). T14 issue-early pipeline.
// Weights: NORMAL cached loads (L2 dedups co-resident duplicate layers).
template <bool XBF16>
__launch_bounds__(256, 2)
__global__ void flex_linear_gemm(const float* __restrict__ x,
                                 const bf16_t* __restrict__ x16,
                                 const float* __restrict__ w,
                                 const int* __restrict__ layer_idx,
                                 const int* __restrict__ perm,
                                 float* __restrict__ out) {
    __shared__ bf16_t Alds[BM * BK + APAD];  // XOR-swizzled [128][64] + pad
    __shared__ bf16_t Blds[BN * BK];         // XOR-swizzled [64][64]

    // ---- XCD-chunked swizzle (2048 % 8 == 0 -> bijective) ----
    const int orig = blockIdx.x;
    const int xcd  = orig & (NXCD - 1);
    const int slot = orig >> 3;                  // 0..255 within XCD
    const int tile = xcd * (NTILES / NXCD) + slot;
    const int yy   = tile / TPP;                 // sorted-position rank
    const int nb   = tile % TPP;                 // output column block (0..31)

    const int s  = perm[yy];
    const int layer = layer_idx[s];

    const float* Bg = w + (size_t)layer * (size_t)(DOUT * DIN) + (size_t)(nb * BN) * DIN;

    const int tid  = threadIdx.x;
    const int lane = tid & 63;
    const int wave = tid >> 6;
    const int wr = (wave >> 1) * 64;    // M offset (0/64)
    const int wc = (wave & 1) * 32;     // N offset (0/32)
    const int lrow = lane & 15;
    const int lk   = (lane >> 4) * 8;

    // ---- hoisted addresses ----
    // A: 4 chunks/thread (128 rows x 8 bf16-chunks); B: 2 chunks/thread (64 rows)
    int offWA[4], offWB[2];
    const float*  pA[4];
    const bf16_t* pA16[4];
    const float*  pB[2];
    #pragma unroll
    for (int i = 0; i < 4; ++i) {
        const int c   = tid + 256 * i;
        const int row = c >> 3;              // 0..127 (b index)
        const int kc8 = (c & 7) * 8;
        offWA[i] = (row * BK + kc8) ^ ((row & 7) << 3);
        const size_t aoff = (size_t)row * (S_DIM * DIN) + (size_t)s * DIN + kc8;
        pA[i]   = x   + aoff;
        pA16[i] = x16 + aoff;
    }
    #pragma unroll
    for (int i = 0; i < 2; ++i) {
        const int c   = tid + 256 * i;
        const int row = c >> 3;              // 0..63 (o index within tile)
        const int kc8 = (c & 7) * 8;
        offWB[i] = (row * BK + kc8) ^ ((row & 7) << 3);
        pB[i] = Bg + (size_t)row * DIN + kc8;
    }
    int offA[2][4], offB[2][2];
    #pragma unroll
    for (int kk = 0; kk < 2; ++kk) {
        #pragma unroll
        for (int m = 0; m < 4; ++m) {
            const int ra = wr + m * 16 + lrow;
            offA[kk][m] = (ra * BK + kk * 32 + lk) ^ ((ra & 7) << 3);
        }
        #pragma unroll
        for (int n = 0; n < 2; ++n) {
            const int rb = wc + n * 16 + lrow;
            offB[kk][n] = (rb * BK + kk * 32 + lk) ^ ((rb & 7) << 3);
        }
    }

    bf16x8 RA16[4];           // in-flight A (bf16 path)
    f32x4  RA[8];             // in-flight A (fp32 fallback)
    f32x4  RB[4];             // in-flight B fp32 (16 floats/thread)
    f32x4  acc[4][2] = {};

    auto issue = [&](int kb) {
        const int koff = kb * BK;
        #pragma unroll
        for (int i = 0; i < 4; ++i) {
            if constexpr (XBF16) {
                RA16[i] = *(const bf16x8*)(pA16[i] + koff);
            } else {
                const float* a = pA[i] + koff;
                RA[2 * i]     = *(const f32x4*)a;
                RA[2 * i + 1] = *(const f32x4*)(a + 4);
            }
        }
        #pragma unroll
        for (int i = 0; i < 2; ++i) {
            const float* b = pB[i] + koff;
            RB[2 * i]     = *(const f32x4*)b;
            RB[2 * i + 1] = *(const f32x4*)(b + 4);
        }
    };
    auto cvt_write = [&]() {
        #pragma unroll
        for (int i = 0; i < 4; ++i) {
            if constexpr (XBF16) {
                *(bf16x8*)&Alds[offWA[i]] = RA16[i];
            } else {
                bf16x8 va;
                #pragma unroll
                for (int j = 0; j < 4; ++j) {
                    va[j]     = (bf16_t)RA[2 * i][j];
                    va[j + 4] = (bf16_t)RA[2 * i + 1][j];
                }
                *(bf16x8*)&Alds[offWA[i]] = va;
            }
        }
        #pragma unroll
        for (int i = 0; i < 2; ++i) {
            bf16x8 vb;
            #pragma unroll
            for (int j = 0; j < 4; ++j) {
                vb[j]     = (bf16_t)RB[2 * i][j];
                vb[j + 4] = (bf16_t)RB[2 * i + 1][j];
            }
            *(bf16x8*)&Blds[offWB[i]] = vb;
        }
    };
    auto compute = [&]() {
        #pragma unroll
        for (int kk = 0; kk < 2; ++kk) {
            bf16x8 af[4], bfr[2];
            #pragma unroll
            for (int m = 0; m < 4; ++m) af[m]  = *(const bf16x8*)&Alds[offA[kk][m]];
            #pragma unroll
            for (int n = 0; n < 2; ++n) bfr[n] = *(const bf16x8*)&Blds[offB[kk][n]];
            #pragma unroll
            for (int m = 0; m < 4; ++m)
                #pragma unroll
                for (int n = 0; n < 2; ++n)
                    acc[m][n] = __builtin_amdgcn_mfma_f32_16x16x32_bf16(af[m], bfr[n], acc[m][n], 0, 0, 0);
        }
    };

    // ---- pipelined main loop: 2 barriers per K-step ----
    issue(0);
    cvt_write();
    for (int kb = 0; kb < NK - 1; ++kb) {
        __syncthreads();
        issue(kb + 1);
        compute();
        __syncthreads();
        cvt_write();
    }
    __syncthreads();
    compute();

    // ---- epilogue (nt stores: out never re-read; keep L2 for x/w) ----
    float* Og = out + (size_t)s * DOUT + (size_t)(nb * BN);
    #pragma unroll
    for (int m = 0; m < 4; ++m) {
        const int rb = wr + m * 16 + (lane >> 4) * 4;
        #pragma unroll
        for (int r = 0; r < 4; ++r) {
            float* orow = Og + (size_t)(rb + r) * (S_DIM * DOUT);
            #pragma unroll
            for (int n = 0; n < 2; ++n)
                __builtin_nontemporal_store(acc[m][n][r], &orow[wc + n * 16 + (lane & 15)]);
        }
    }
}

extern "C" void kernel_launch(void* const* d_in, const int* in_sizes, int n_in,
                              void* d_out, int out_size, void* d_ws, size_t ws_size,
                              hipStream_t stream) {
    const float* x         = (const float*)d_in[0];
    const float* w         = (const float*)d_in[1];
    const int*   layer_idx = (const int*)d_in[2];
    float*       out       = (float*)d_out;

    int*    perm = (int*)d_ws;
    bf16_t* x16  = (bf16_t*)((char*)d_ws + 512);
    const size_t need = 512 + (size_t)B_DIM * S_DIM * DIN * sizeof(bf16_t);

    rank_sort<<<1, S_DIM, 0, stream>>>(layer_idx, perm);

    if (ws_size >= need) {
        convert_x<<<(B_DIM * S_DIM * DIN / 8) / 256, 256, 0, stream>>>(x, x16);
        flex_linear_gemm<true><<<NTILES, dim3(256), 0, stream>>>(x, x16, w, layer_idx, perm, out);
    } else {
        flex_linear_gemm<false><<<NTILES, dim3(256), 0, stream>>>(x, x16, w, layer_idx, perm, out);
    }
}